// Round 3
// baseline (1621.098 us; speedup 1.0000x reference)
//
#include <hip/hip_runtime.h>

#define N_ATOMS 30000
#define NJ 12
#define FDIM 128

typedef __attribute__((ext_vector_type(8))) short short8;
typedef __attribute__((ext_vector_type(4))) float f32x4;

// ws layout (bytes)
#define WFRAG_OFF 0          // 8 mats * 32768 B  (bf16 frag-linear)
#define GFRAG_OFF 262144     // 3 mats * 8192  B
#define MFRAG_OFF 286720     // 2 mats * 32768 B
#define MTMP_OFF  352256     // 2 mats * 65536 B  (f32 M_p, M_d)
#define FEA_OFF   483328     // 3 * 30000*128 bf16 (s,p,d fea)
#define FEA_ELEMS 3840000
#define CFEA_OFF  23523328   // 30000*128 f32 (final_c)

__device__ __forceinline__ unsigned short f2b(float f){
  unsigned u = __builtin_bit_cast(unsigned, f);
  u = (u + 0x7fffu + ((u >> 16) & 1u)) >> 16;
  return (unsigned short)u;
}
__device__ __forceinline__ float b2f(unsigned short s){
  unsigned u = ((unsigned)s) << 16;
  return __builtin_bit_cast(float, u);
}
__device__ __forceinline__ unsigned pack_bf2(float a, float b){
  unsigned ua = __builtin_bit_cast(unsigned, a);
  unsigned ub = __builtin_bit_cast(unsigned, b);
  ua = (ua + 0x7fffu + ((ua >> 16) & 1u)) >> 16;
  ub = (ub + 0x7fffu + ((ub >> 16) & 1u)) & 0xffff0000u;
  return ua | ub;
}
__device__ __forceinline__ float silu_f(float x){ return x / (1.0f + __expf(-x)); }
// gBuf tile swizzle: spreads (a, k-high) bits into bank bits; bijective, >=bit4 only
__device__ __forceinline__ int swz(int a){
  return a ^ ((((a >> 8) ^ (a >> 11)) & 7) << 4);
}
// wave-private LDS fence: cross-lane write->read visibility within one wave
__device__ __forceinline__ void lds_fence(){
  __builtin_amdgcn_sched_barrier(0);
  asm volatile("s_waitcnt lgkmcnt(0)" ::: "memory");
  __builtin_amdgcn_sched_barrier(0);
}

struct Ptr8 { const float* p[8]; };
struct Ptr3 { const float* p[3]; };
struct Bias { const float* br[4]; const float* b1[4]; };

// ---------------- kernel 0a: M = P1*P2^T / D1*D2^T, plus W/G fragment packing --
__global__ __launch_bounds__(256) void k_prep(
    const float* __restrict__ P1, const float* __restrict__ P2,
    const float* __restrict__ D1, const float* __restrict__ D2,
    Ptr8 w8, Ptr3 g3, char* __restrict__ ws)
{
  int b = blockIdx.x, t = threadIdx.x;
  if (b < 16){
    int mat = b >> 3, rb = b & 7;
    const float* A = mat ? D1 : P1;
    const float* B = mat ? D2 : P2;
    float* MT = (float*)(ws + MTMP_OFF) + (size_t)mat*16384;
    for (int it = 0; it < 8; ++it){
      int o = it*256 + t;
      int row = rb*16 + (o >> 7), col = o & 127;
      const float4* ar = (const float4*)(A + (size_t)row*128);
      const float4* br = (const float4*)(B + (size_t)col*128);
      float s = 0.f;
      #pragma unroll 8
      for (int q = 0; q < 32; ++q){
        float4 a = ar[q], c = br[q];
        s += a.x*c.x + a.y*c.y + a.z*c.z + a.w*c.w;
      }
      MT[(size_t)row*128 + col] = s;
    }
  } else if (b < 24){
    int mat = b - 16;
    const float* W = w8.p[mat];
    unsigned short* dst = (unsigned short*)(ws + WFRAG_OFF) + (size_t)mat*16384;
    for (int it = 0; it < 64; ++it){
      int idx = it*256 + t;
      int i = idx & 7, ln = (idx >> 3) & 63, ft = (idx >> 9) & 7, ks = idx >> 12;
      int f = ft*16 + (ln & 15);
      int k = ks*32 + ((ln >> 4) & 3)*8 + i;
      dst[idx] = f2b(W[(size_t)f*128 + k]);
    }
  } else {
    int mat = b - 24;
    const float* G = g3.p[mat];
    unsigned short* dst = (unsigned short*)(ws + GFRAG_OFF) + (size_t)mat*4096;
    for (int it = 0; it < 16; ++it){
      int idx = it*256 + t;
      int i = idx & 7, ln = (idx >> 3) & 63, ft = idx >> 9;
      int f = ft*16 + (ln & 15);
      int k = ((ln >> 4) & 3)*8 + i;
      dst[idx] = f2b(G[(size_t)f*32 + k]);
    }
  }
}

// ---------------- kernel 0b: fragment-pack M_p / M_d ---------------------------
__global__ __launch_bounds__(256) void k_mfrag(char* __restrict__ ws)
{
  int mat = blockIdx.x, t = threadIdx.x;
  const float* MT = (const float*)(ws + MTMP_OFF) + (size_t)mat*16384;
  unsigned short* dst = (unsigned short*)(ws + MFRAG_OFF) + (size_t)mat*16384;
  for (int it = 0; it < 64; ++it){
    int idx = it*256 + t;
    int i = idx & 7, ln = (idx >> 3) & 63, ft = (idx >> 9) & 7, ks = idx >> 12;
    int fp = ft*16 + (ln & 15);
    int k = ks*32 + ((ln >> 4) & 3)*8 + i;
    dst[idx] = f2b(MT[(size_t)k*128 + fp]);
  }
}

// ---------------- kernel 1: 4 ResMLP channels fused, barrier-free --------------
__global__ __launch_bounds__(256, 5) void k_resmlp(
    const float* __restrict__ x, char* __restrict__ ws, Bias bs)
{
  __shared__ alignas(16) char sm[32768];
  const int tid = threadIdx.x, lane = tid & 63, wid = tid >> 6;
  const int lo = lane & 15, hi = lane >> 4;
  const int rowbase = (int)blockIdx.x*64 + wid*16;
  char* xL = sm + wid*8192;
  char* hL = xL + 4096;

  // stage silu(x) frag-linear (once for all 4 channels)
  #pragma unroll
  for (int it = 0; it < 8; ++it){
    int e4 = it*64 + lane;
    int row = e4 >> 5, k0 = (e4 & 31)*4;
    int grow = rowbase + row; if (grow >= N_ATOMS) grow = N_ATOMS-1;
    float4 v = *(const float4*)(x + (size_t)grow*FDIM + k0);
    uint2 u;
    u.x = pack_bf2(silu_f(v.x), silu_f(v.y));
    u.y = pack_bf2(silu_f(v.z), silu_f(v.w));
    int ks = k0 >> 5, h2 = (k0 >> 3) & 3, i0 = k0 & 7, lanep = row | (h2 << 4);
    *(uint2*)(xL + ks*1024 + lanep*16 + i0*2) = u;
  }
  lds_fence();
  short8 A[4];
  #pragma unroll
  for (int ks = 0; ks < 4; ++ks) A[ks] = *(const short8*)(xL + ks*1024 + lane*16);

  // x values for the residual (reused by all channels)
  float xr[8][4];
  #pragma unroll
  for (int ft = 0; ft < 8; ++ft){
    #pragma unroll
    for (int r = 0; r < 4; ++r){
      int grow = rowbase + hi*4 + r; if (grow >= N_ATOMS) grow = N_ATOMS-1;
      xr[ft][r] = x[(size_t)grow*FDIM + ft*16 + lo];
    }
  }
  float* cfea = (float*)(ws + CFEA_OFF);

  #pragma unroll
  for (int ch = 0; ch < 4; ++ch){
    const char* wrp = ws + (size_t)(ch*2)*32768;
    const char* w1p = ws + (size_t)(ch*2 + 1)*32768;
    const float* brp = bs.br[ch];
    const float* b1p = bs.b1[ch];

    f32x4 acc[8];
    #pragma unroll
    for (int ft = 0; ft < 8; ++ft) acc[ft] = (f32x4){0.f,0.f,0.f,0.f};
    #pragma unroll
    for (int ks = 0; ks < 4; ++ks){
      #pragma unroll
      for (int ft = 0; ft < 8; ++ft){
        short8 B = *(const short8*)(wrp + (size_t)(((ks*8 + ft)*64 + lane)*16));
        acc[ft] = __builtin_amdgcn_mfma_f32_16x16x32_bf16(A[ks], B, acc[ft], 0, 0, 0);
      }
    }
    // epi1: h = x + silu(x)@wr^T + br ; stage silu(h)
    #pragma unroll
    for (int ft = 0; ft < 8; ++ft){
      int f = ft*16 + lo;
      float bias = brp[f];
      #pragma unroll
      for (int r = 0; r < 4; ++r){
        float h = acc[ft][r] + xr[ft][r] + bias;
        float sh = silu_f(h);
        int ks2 = f >> 5, h2 = (f >> 3) & 3, i2 = f & 7, lanep = (hi*4 + r) | (h2 << 4);
        *(unsigned short*)(hL + ks2*1024 + lanep*16 + i2*2) = f2b(sh);
      }
    }
    lds_fence();
    short8 A2[4];
    #pragma unroll
    for (int ks = 0; ks < 4; ++ks) A2[ks] = *(const short8*)(hL + ks*1024 + lane*16);

    f32x4 acc2[8];
    #pragma unroll
    for (int ft = 0; ft < 8; ++ft) acc2[ft] = (f32x4){0.f,0.f,0.f,0.f};
    #pragma unroll
    for (int ks = 0; ks < 4; ++ks){
      #pragma unroll
      for (int ft = 0; ft < 8; ++ft){
        short8 B = *(const short8*)(w1p + (size_t)(((ks*8 + ft)*64 + lane)*16));
        acc2[ft] = __builtin_amdgcn_mfma_f32_16x16x32_bf16(A2[ks], B, acc2[ft], 0, 0, 0);
      }
    }
    if (ch == 0){
      #pragma unroll
      for (int ft = 0; ft < 8; ++ft){
        int f = ft*16 + lo;
        float bb = b1p[f];
        #pragma unroll
        for (int r = 0; r < 4; ++r){
          int grow = rowbase + hi*4 + r; if (grow >= N_ATOMS) grow = N_ATOMS-1;
          cfea[(size_t)grow*FDIM + f] = acc2[ft][r] + bb;
        }
      }
    } else {
      unsigned short* fea = (unsigned short*)(ws + FEA_OFF) + (size_t)(ch-1)*FEA_ELEMS;
      #pragma unroll
      for (int ft = 0; ft < 8; ++ft){
        int f = ft*16 + lo;
        float bb = b1p[f];
        #pragma unroll
        for (int r = 0; r < 4; ++r){
          int grow = rowbase + hi*4 + r; if (grow >= N_ATOMS) grow = N_ATOMS-1;
          fea[(size_t)grow*FDIM + f] = f2b(acc2[ft][r] + bb);
        }
      }
    }
  }
}

// ---------------- kernel 2 helpers ---------------------------------------------
template<int NA>
__device__ __forceinline__ void jsum_acc(const short8* Af, const short8* Bg,
    const unsigned short (&w)[8][4], char* accB, int lane)
{
  const f32x4 z4 = {0.f,0.f,0.f,0.f};
  #pragma unroll
  for (int ft = 0; ft < 8; ++ft){
    float w0 = b2f(w[ft][0]), w1 = b2f(w[ft][1]), w2 = b2f(w[ft][2]), w3 = b2f(w[ft][3]);
    #pragma unroll
    for (int a = 0; a < NA; ++a){
      f32x4 c = __builtin_amdgcn_mfma_f32_16x16x32_bf16(Af[a], Bg[ft], z4, 0, 0, 0);
      float p = c[0]*w0 + c[1]*w1 + c[2]*w2 + c[3]*w3;
      p += __shfl_xor(p, 16);
      p += __shfl_xor(p, 32);
      if (lane < 16) *(unsigned short*)(accB + a*272 + ft*32 + lane*2) = f2b(p);
    }
  }
}

template<int NAq>
__device__ __forceinline__ float quad_head(const char* mb, const char* accB,
    int lane, int lo, int hi)
{
  short8 Aq[4];
  #pragma unroll
  for (int ks = 0; ks < 4; ++ks){
    short8 aa = (short8){0,0,0,0,0,0,0,0};
    if (lo < NAq) aa = *(const short8*)(accB + lo*272 + ks*64 + hi*16);
    Aq[ks] = aa;
  }
  f32x4 acc2[8];
  #pragma unroll
  for (int ft = 0; ft < 8; ++ft) acc2[ft] = (f32x4){0.f,0.f,0.f,0.f};
  #pragma unroll
  for (int ks = 0; ks < 4; ++ks){
    #pragma unroll
    for (int ft = 0; ft < 8; ++ft){
      short8 B = *(const short8*)(mb + (size_t)(((ks*8 + ft)*64 + lane)*16));
      acc2[ft] = __builtin_amdgcn_mfma_f32_16x16x32_bf16(Aq[ks], B, acc2[ft], 0, 0, 0);
    }
  }
  float sc = 0.f;
  #pragma unroll
  for (int ft = 0; ft < 8; ++ft){
    #pragma unroll
    for (int r = 0; r < 4; ++r){
      int a = hi*4 + r;
      if (hi < 2 && a < NAq)
        sc += acc2[ft][r] * b2f(*(const unsigned short*)(accB + a*272 + ft*32 + lo*2));
    }
  }
  #pragma unroll
  for (int m = 1; m < 64; m <<= 1) sc += __shfl_xor(sc, m);
  return sc;
}

// ---------------- kernel 2: 4 atoms/wave, barrier-free, prefetched -------------
__global__ __launch_bounds__(256, 6) void k_main(
    const float* __restrict__ gs, const float* __restrict__ gp,
    const float* __restrict__ gd, const int* __restrict__ nbr,
    char* __restrict__ ws, float* __restrict__ out)
{
  __shared__ alignas(16) char sm[4*6480];
  const int tid = threadIdx.x, lane = tid & 63, wid = tid >> 6;
  const int lo = lane & 15, hi = lane >> 4;
  char* gBuf = sm + wid*6480;        // 5 tiles * 1024 B (swizzled)
  char* accB = gBuf + 5120;          // 5 rows * 272 B bf16
  const char* gfrag = ws + GFRAG_OFF;
  const char* mfrag = ws + MFRAG_OFF;
  const unsigned short* feaS = (const unsigned short*)(ws + FEA_OFF);
  const unsigned short* feaP = feaS + FEA_ELEMS;
  const unsigned short* feaD = feaS + 2*FEA_ELEMS;
  const float* cfea = (const float*)(ws + CFEA_OFF);
  const f32x4 z4 = {0.f,0.f,0.f,0.f};

  // zero whole wave slab once (j>=12 rows must be 0; accB rows 3-7 read-by-zero)
  #pragma unroll
  for (int t = 0; t < 6; ++t) *(f32x4*)(gBuf + (t*64 + lane)*16) = z4;
  if (lane < 21) *(f32x4*)(gBuf + (384 + lane)*16) = z4;

  // --- hoisted staging tables (per-lane, atom-independent) ---
  int t0l[3];
  #pragma unroll
  for (int s = 0; s < 3; ++s){
    int j = s*4 + hi, k = 2*lo;
    t0l[s] = swz(((j | ((k >> 3) << 4)) << 4) | ((k & 7) << 1));
  }
  int t1l[9], t1o[9];
  #pragma unroll
  for (int s = 0; s < 9; ++s){
    int pidx = s*64 + lane;
    int j = pidx/48, r = pidx - j*48, kp = r/3, a = r - kp*3, k = kp*2;
    t1l[s] = swz(a*1024 + (((j | ((k >> 3) << 4)) << 4) | ((k & 7) << 1)));
    t1o[s] = (j*96 + kp*6 + a)*4;
  }
  int t2l[15], t2o[15];
  #pragma unroll
  for (int s = 0; s < 15; ++s){
    int pidx = s*64 + lane;
    int j = pidx/80, r = pidx - j*80, kp = r/5, a = r - kp*5, k = kp*2;
    t2l[s] = swz(a*1024 + (((j | ((k >> 3) << 4)) << 4) | ((k & 7) << 1)));
    t2o[s] = (j*160 + kp*10 + a)*4;
  }

  const int aw = (int)blockIdx.x*4 + wid;
  const int au0 = __builtin_amdgcn_readfirstlane(aw)*4;

  float2 rg0[3]; float rg1a[9], rg1b[9], rg2a[15], rg2b[15];
  int njN[4], njC[4];
  unsigned short wS[8][4], wP[8][4], wD[8][4];

#define LOAD_G(AU) do { \
    const float* g0p_ = gs + (size_t)(AU)*384; \
    _Pragma("unroll") for (int s = 0; s < 3; ++s) rg0[s] = *(const float2*)(g0p_ + (s*64 + lane)*2); \
    const char* g1p_ = (const char*)(gp + (size_t)(AU)*1152); \
    _Pragma("unroll") for (int s = 0; s < 9; ++s){ \
      rg1a[s] = *(const float*)(g1p_ + t1o[s]); rg1b[s] = *(const float*)(g1p_ + t1o[s] + 12); } \
    const char* g2p_ = (const char*)(gd + (size_t)(AU)*1920); \
    _Pragma("unroll") for (int s = 0; s < 15; ++s){ \
      rg2a[s] = *(const float*)(g2p_ + t2o[s]); rg2b[s] = *(const float*)(g2p_ + t2o[s] + 20); } \
  } while(0)

#define LOAD_NBR(AU) do { \
    _Pragma("unroll") for (int r = 0; r < 4; ++r){ \
      int jj = hi*4 + r; jj = jj > 11 ? 11 : jj; \
      njN[r] = nbr[(size_t)(AU)*NJ + jj]; } \
  } while(0)

#define LOAD_W(W, FEA, NJA) do { \
    _Pragma("unroll") for (int r = 0; r < 4; ++r){ \
      const unsigned short* rp_ = (FEA) + (size_t)NJA[r]*FDIM + lo; \
      _Pragma("unroll") for (int ft = 0; ft < 8; ++ft) W[ft][r] = rp_[ft*16]; } \
  } while(0)

  // prologue: atom au0
  LOAD_G(au0);
  LOAD_NBR(au0);
  #pragma unroll
  for (int r = 0; r < 4; ++r) njC[r] = njN[r];
  LOAD_W(wS, feaS, njC);

  #pragma unroll 1
  for (int ai = 0; ai < 4; ++ai){
    const int au = au0 + ai;
    int aun = au + 1; if (aun > N_ATOMS-1) aun = N_ATOMS-1;
    #pragma unroll
    for (int r = 0; r < 4; ++r) njC[r] = njN[r];   // nbr of current atom
    LOAD_NBR(aun);                                  // issue nbr of next atom

    // stage0: tile0 (s channel)
    #pragma unroll
    for (int s = 0; s < 3; ++s)
      *(unsigned*)(gBuf + t0l[s]) = pack_bf2(rg0[s].x, rg0[s].y);
    lds_fence();
    short8 Af0 = *(const short8*)(gBuf + swz(lane*16));
    // stage1: tiles 0-2 (p channel) — overlaps G0 compute
    #pragma unroll
    for (int s = 0; s < 9; ++s)
      *(unsigned*)(gBuf + t1l[s]) = pack_bf2(rg1a[s], rg1b[s]);
    LOAD_W(wP, feaP, njC);

    // G0 jsum → outv0/outv1
    float outv0 = 0.f, outv1 = 0.f;
    {
      short8 Bg[8];
      #pragma unroll
      for (int ft = 0; ft < 8; ++ft) Bg[ft] = *(const short8*)(gfrag + (ft*64 + lane)*16);
      #pragma unroll
      for (int ft = 0; ft < 8; ++ft){
        float w0 = b2f(wS[ft][0]), w1 = b2f(wS[ft][1]), w2 = b2f(wS[ft][2]), w3 = b2f(wS[ft][3]);
        f32x4 c = __builtin_amdgcn_mfma_f32_16x16x32_bf16(Af0, Bg[ft], z4, 0, 0, 0);
        float p = c[0]*w0 + c[1]*w1 + c[2]*w2 + c[3]*w3;
        p += __shfl_xor(p, 16);
        p += __shfl_xor(p, 32);
        if (ft == hi)     outv0 += p;
        if (ft == hi + 4) outv1 += p;
      }
    }
    lds_fence();
    short8 Af1[3];
    #pragma unroll
    for (int a = 0; a < 3; ++a) Af1[a] = *(const short8*)(gBuf + swz(a*1024 + lane*16));
    // stage2: tiles 0-4 (d channel) — overlaps G1 compute
    #pragma unroll
    for (int s = 0; s < 15; ++s)
      *(unsigned*)(gBuf + t2l[s]) = pack_bf2(rg2a[s], rg2b[s]);
    LOAD_W(wD, feaD, njC);
    {
      short8 Bg[8];
      #pragma unroll
      for (int ft = 0; ft < 8; ++ft) Bg[ft] = *(const short8*)(gfrag + 8192 + (ft*64 + lane)*16);
      jsum_acc<3>(Af1, Bg, wP, accB, lane);
    }
    lds_fence();
    short8 Af2[5];
    #pragma unroll
    for (int a = 0; a < 5; ++a) Af2[a] = *(const short8*)(gBuf + swz(a*1024 + lane*16));
    float qp = quad_head<3>(mfrag, accB, lane, lo, hi);
    {
      short8 Bg[8];
      #pragma unroll
      for (int ft = 0; ft < 8; ++ft) Bg[ft] = *(const short8*)(gfrag + 16384 + (ft*64 + lane)*16);
      jsum_acc<5>(Af2, Bg, wD, accB, lane);
    }
    lds_fence();
    float qd = quad_head<5>(mfrag + 32768, accB, lane, lo, hi);

    size_t ob = (size_t)au*FDIM;
    float add = qp + qd;
    out[ob + lane]      = cfea[ob + lane]      + outv0 + add;
    out[ob + 64 + lane] = cfea[ob + 64 + lane] + outv1 + add;

    // prefetch next atom's g-data + s-weights (hidden under this iter's tail)
    LOAD_G(aun);
    LOAD_W(wS, feaS, njN);
  }
#undef LOAD_G
#undef LOAD_NBR
#undef LOAD_W
}

// ---------------- launch -------------------------------------------------------
extern "C" void kernel_launch(void* const* d_in, const int* in_sizes, int n_in,
                              void* d_out, int out_size, void* d_ws, size_t ws_size,
                              hipStream_t stream)
{
  const float* atom_fea = (const float*)d_in[0];
  const int*   nbr      = (const int*)d_in[1];
  const float* gs = (const float*)d_in[2];
  const float* gp = (const float*)d_in[3];
  const float* gd = (const float*)d_in[4];
  const float* Gs = (const float*)d_in[5];
  const float* Gp = (const float*)d_in[6];
  const float* Gd = (const float*)d_in[7];
  const float* P1 = (const float*)d_in[8];
  const float* P2 = (const float*)d_in[9];
  const float* D1 = (const float*)d_in[10];
  const float* D2 = (const float*)d_in[11];

  Ptr8 w8;
  w8.p[0] = (const float*)d_in[12];  // c_wr
  w8.p[1] = (const float*)d_in[14];  // c_w1
  w8.p[2] = (const float*)d_in[16];  // s_wr
  w8.p[3] = (const float*)d_in[18];  // s_w1
  w8.p[4] = (const float*)d_in[20];  // p_wr
  w8.p[5] = (const float*)d_in[22];  // p_w1
  w8.p[6] = (const float*)d_in[24];  // d_wr
  w8.p[7] = (const float*)d_in[26];  // d_w1
  Ptr3 g3; g3.p[0] = Gs; g3.p[1] = Gp; g3.p[2] = Gd;
  Bias bs;
  bs.br[0] = (const float*)d_in[13]; bs.b1[0] = (const float*)d_in[15];
  bs.br[1] = (const float*)d_in[17]; bs.b1[1] = (const float*)d_in[19];
  bs.br[2] = (const float*)d_in[21]; bs.b1[2] = (const float*)d_in[23];
  bs.br[3] = (const float*)d_in[25]; bs.b1[3] = (const float*)d_in[27];

  char* ws = (char*)d_ws;
  float* out = (float*)d_out;

  k_prep <<<27, 256, 0, stream>>>(P1, P2, D1, D2, w8, g3, ws);
  k_mfrag<<<2, 256, 0, stream>>>(ws);
  k_resmlp<<<(N_ATOMS + 63)/64, 256, 0, stream>>>(atom_fea, ws, bs);
  k_main <<<N_ATOMS/16, 256, 0, stream>>>(gs, gp, gd, nbr, ws, out);
}

// Round 4
// 372.894 us; speedup vs baseline: 4.3473x; 4.3473x over previous
//
#include <hip/hip_runtime.h>

#define N_ATOMS 30000
#define NJ 12
#define FDIM 128

typedef __attribute__((ext_vector_type(8))) short short8;
typedef __attribute__((ext_vector_type(4))) float f32x4;

// ws layout (bytes)
#define WFRAG_OFF 0          // 8 mats * 32768 B  (bf16 frag-linear)
#define GFRAG_OFF 262144     // 3 mats * 8192  B
#define MFRAG_OFF 286720     // 2 mats * 32768 B
#define FEA_OFF   483328     // 3 * 30000*128 bf16 (s,p,d fea)
#define FEA_ELEMS 3840000
#define CFEA_OFF  23523328   // 30000*128 f32 (final_c)

__device__ __forceinline__ unsigned short f2b(float f){
  unsigned u = __builtin_bit_cast(unsigned, f);
  u = (u + 0x7fffu + ((u >> 16) & 1u)) >> 16;
  return (unsigned short)u;
}
__device__ __forceinline__ float b2f(unsigned short s){
  unsigned u = ((unsigned)s) << 16;
  return __builtin_bit_cast(float, u);
}
__device__ __forceinline__ unsigned pack_bf2(float a, float b){
  unsigned ua = __builtin_bit_cast(unsigned, a);
  unsigned ub = __builtin_bit_cast(unsigned, b);
  ua = (ua + 0x7fffu + ((ua >> 16) & 1u)) >> 16;
  ub = (ub + 0x7fffu + ((ub >> 16) & 1u)) & 0xffff0000u;
  return ua | ub;
}
__device__ __forceinline__ float silu_f(float x){ return x / (1.0f + __expf(-x)); }
__device__ __forceinline__ void lds_fence(){
  __builtin_amdgcn_sched_barrier(0);
  asm volatile("s_waitcnt lgkmcnt(0)" ::: "memory");
  __builtin_amdgcn_sched_barrier(0);
}
__device__ __forceinline__ short8 frag4(unsigned d0, unsigned d1, unsigned d2, unsigned d3, bool valid){
  if (!valid){ d0 = 0u; d1 = 0u; d2 = 0u; d3 = 0u; }
  uint4 u; u.x = d0; u.y = d1; u.z = d2; u.w = d3;
  return __builtin_bit_cast(short8, u);
}

struct Ptr8 { const float* p[8]; };
struct Ptr3 { const float* p[3]; };
struct Bias { const float* br[4]; const float* b1[4]; };

// ---------------- kernel 0: M=P1*P2^T / D1*D2^T (direct frag), W/G frag pack ---
__global__ __launch_bounds__(256) void k_prep(
    const float* __restrict__ P1, const float* __restrict__ P2,
    const float* __restrict__ D1, const float* __restrict__ D2,
    Ptr8 w8, Ptr3 g3, char* __restrict__ ws)
{
  int b = blockIdx.x, t = threadIdx.x;
  if (b < 16){
    int mat = b >> 3, rb = b & 7;
    const float* A = mat ? D1 : P1;
    const float* B = mat ? D2 : P2;
    unsigned short* dst = (unsigned short*)(ws + MFRAG_OFF) + (size_t)mat*16384;
    for (int it = 0; it < 8; ++it){
      int o = it*256 + t;
      int row = rb*16 + (o >> 7), col = o & 127;   // row = k, col = f'
      const float4* ar = (const float4*)(A + (size_t)row*128);
      const float4* br = (const float4*)(B + (size_t)col*128);
      float s = 0.f;
      #pragma unroll 8
      for (int q = 0; q < 32; ++q){
        float4 a = ar[q], c = br[q];
        s += a.x*c.x + a.y*c.y + a.z*c.z + a.w*c.w;
      }
      int ks = row >> 5, ft = col >> 4;
      int ln = (col & 15) | (((row >> 3) & 3) << 4);
      dst[(size_t)(((ks*8 + ft)*64 + ln)*8 + (row & 7))] = f2b(s);
    }
  } else if (b < 24){
    int mat = b - 16;
    const float* W = w8.p[mat];
    unsigned short* dst = (unsigned short*)(ws + WFRAG_OFF) + (size_t)mat*16384;
    for (int it = 0; it < 64; ++it){
      int idx = it*256 + t;
      int i = idx & 7, ln = (idx >> 3) & 63, ft = (idx >> 9) & 7, ks = idx >> 12;
      int f = ft*16 + (ln & 15);
      int k = ks*32 + ((ln >> 4) & 3)*8 + i;
      dst[idx] = f2b(W[(size_t)f*128 + k]);
    }
  } else {
    int mat = b - 24;
    const float* G = g3.p[mat];
    unsigned short* dst = (unsigned short*)(ws + GFRAG_OFF) + (size_t)mat*4096;
    for (int it = 0; it < 16; ++it){
      int idx = it*256 + t;
      int i = idx & 7, ln = (idx >> 3) & 63, ft = idx >> 9;
      int f = ft*16 + (ln & 15);
      int k = ((ln >> 4) & 3)*8 + i;
      dst[idx] = f2b(G[(size_t)f*32 + k]);
    }
  }
}

// ---------------- kernel 1: 4 ResMLP channels fused, barrier-free --------------
__global__ __launch_bounds__(256, 4) void k_resmlp(
    const float* __restrict__ x, char* __restrict__ ws, Bias bs)
{
  __shared__ alignas(16) char sm[32768];
  const int tid = threadIdx.x, lane = tid & 63;
  const int wid = __builtin_amdgcn_readfirstlane(tid >> 6);
  const int lo = lane & 15, hi = lane >> 4;
  const int rowbase = (int)blockIdx.x*64 + wid*16;
  char* xL = sm + wid*8192;
  char* hL = xL + 4096;

  // stage silu(x) frag-linear (once for all 4 channels)
  #pragma unroll
  for (int it = 0; it < 8; ++it){
    int e4 = it*64 + lane;
    int row = e4 >> 5, k0 = (e4 & 31)*4;
    int grow = rowbase + row; if (grow >= N_ATOMS) grow = N_ATOMS-1;
    float4 v = *(const float4*)(x + (size_t)grow*FDIM + k0);
    uint2 u;
    u.x = pack_bf2(silu_f(v.x), silu_f(v.y));
    u.y = pack_bf2(silu_f(v.z), silu_f(v.w));
    int ks = k0 >> 5, h2 = (k0 >> 3) & 3, i0 = k0 & 7, lanep = row | (h2 << 4);
    *(uint2*)(xL + ks*1024 + lanep*16 + i0*2) = u;
  }
  lds_fence();
  short8 A[4];
  #pragma unroll
  for (int ks = 0; ks < 4; ++ks) A[ks] = *(const short8*)(xL + ks*1024 + lane*16);

  float* cfea = (float*)(ws + CFEA_OFF);

  #pragma unroll 1
  for (int ch = 0; ch < 4; ++ch){
    const char* wrp = ws + (size_t)(ch*2)*32768;
    const char* w1p = ws + (size_t)(ch*2 + 1)*32768;
    const float* brp = bs.br[ch];
    const float* b1p = bs.b1[ch];

    f32x4 acc[8];
    #pragma unroll
    for (int ft = 0; ft < 8; ++ft) acc[ft] = (f32x4){0.f,0.f,0.f,0.f};
    #pragma unroll
    for (int ks = 0; ks < 4; ++ks){
      #pragma unroll
      for (int ft = 0; ft < 8; ++ft){
        short8 B = *(const short8*)(wrp + (size_t)(((ks*8 + ft)*64 + lane)*16));
        acc[ft] = __builtin_amdgcn_mfma_f32_16x16x32_bf16(A[ks], B, acc[ft], 0, 0, 0);
      }
    }
    // epi1: h = x + silu(x)@wr^T + br ; stage silu(h)
    #pragma unroll
    for (int ft = 0; ft < 8; ++ft){
      int f = ft*16 + lo;
      float bias = brp[f];
      #pragma unroll
      for (int r = 0; r < 4; ++r){
        int grow = rowbase + hi*4 + r; if (grow >= N_ATOMS) grow = N_ATOMS-1;
        float h = acc[ft][r] + x[(size_t)grow*FDIM + f] + bias;
        float sh = silu_f(h);
        int ks2 = f >> 5, h2 = (f >> 3) & 3, i2 = f & 7, lanep = (hi*4 + r) | (h2 << 4);
        *(unsigned short*)(hL + ks2*1024 + lanep*16 + i2*2) = f2b(sh);
      }
    }
    lds_fence();
    short8 A2[4];
    #pragma unroll
    for (int ks = 0; ks < 4; ++ks) A2[ks] = *(const short8*)(hL + ks*1024 + lane*16);

    f32x4 acc2[8];
    #pragma unroll
    for (int ft = 0; ft < 8; ++ft) acc2[ft] = (f32x4){0.f,0.f,0.f,0.f};
    #pragma unroll
    for (int ks = 0; ks < 4; ++ks){
      #pragma unroll
      for (int ft = 0; ft < 8; ++ft){
        short8 B = *(const short8*)(w1p + (size_t)(((ks*8 + ft)*64 + lane)*16));
        acc2[ft] = __builtin_amdgcn_mfma_f32_16x16x32_bf16(A2[ks], B, acc2[ft], 0, 0, 0);
      }
    }
    lds_fence();   // A2 reads done before next ch overwrites hL
    if (ch == 0){
      #pragma unroll
      for (int ft = 0; ft < 8; ++ft){
        int f = ft*16 + lo;
        float bb = b1p[f];
        #pragma unroll
        for (int r = 0; r < 4; ++r){
          int grow = rowbase + hi*4 + r; if (grow >= N_ATOMS) grow = N_ATOMS-1;
          cfea[(size_t)grow*FDIM + f] = acc2[ft][r] + bb;
        }
      }
    } else {
      unsigned short* fea = (unsigned short*)(ws + FEA_OFF) + (size_t)(ch-1)*FEA_ELEMS;
      #pragma unroll
      for (int ft = 0; ft < 8; ++ft){
        int f = ft*16 + lo;
        float bb = b1p[f];
        #pragma unroll
        for (int r = 0; r < 4; ++r){
          int grow = rowbase + hi*4 + r; if (grow >= N_ATOMS) grow = N_ATOMS-1;
          fea[(size_t)grow*FDIM + f] = f2b(acc2[ft][r] + bb);
        }
      }
    }
  }
}

// ---------------- kernel 2 helpers ---------------------------------------------
__device__ __forceinline__ void stage_fea(char* buf, const unsigned short* fea,
                                          int nb, int lane)
{
  #pragma unroll
  for (int j = 0; j < NJ; ++j){
    int nj = __shfl(nb, j);
    unsigned v = *(const unsigned*)(fea + (size_t)nj*FDIM + lane*2);
    *(unsigned*)(buf + j*264 + lane*4) = v;
  }
}

template<int NA>
__device__ __forceinline__ void jsum_acc(const short8* Af, const char* gfragG,
    const char* buf, const int* rowoff, char* accB, int lane)
{
  const f32x4 z4 = {0.f,0.f,0.f,0.f};
  short8 Bg[8];
  #pragma unroll
  for (int ft = 0; ft < 8; ++ft)
    Bg[ft] = *(const short8*)(gfragG + (size_t)((ft*64 + lane)*16));
  const int lo = lane & 15;
  #pragma unroll
  for (int ft = 0; ft < 8; ++ft){
    int fo = (ft*16 + lo)*2;
    float w0 = b2f(*(const unsigned short*)(buf + rowoff[0] + fo));
    float w1 = b2f(*(const unsigned short*)(buf + rowoff[1] + fo));
    float w2 = b2f(*(const unsigned short*)(buf + rowoff[2] + fo));
    float w3 = b2f(*(const unsigned short*)(buf + rowoff[3] + fo));
    #pragma unroll
    for (int a = 0; a < NA; ++a){
      f32x4 c = __builtin_amdgcn_mfma_f32_16x16x32_bf16(Af[a], Bg[ft], z4, 0, 0, 0);
      float p = c[0]*w0 + c[1]*w1 + c[2]*w2 + c[3]*w3;
      p += __shfl_xor(p, 16);
      p += __shfl_xor(p, 32);
      if (lane < 16) *(unsigned short*)(accB + a*272 + ft*32 + lane*2) = f2b(p);
    }
  }
}

template<int NAq>
__device__ __forceinline__ float quad_head(const char* mb, const char* accB,
    int lane, int lo, int hi)
{
  short8 Aq[4];
  #pragma unroll
  for (int ks = 0; ks < 4; ++ks){
    short8 aa = (short8){0,0,0,0,0,0,0,0};
    if (lo < NAq) aa = *(const short8*)(accB + lo*272 + ks*64 + hi*16);
    Aq[ks] = aa;
  }
  f32x4 acc2[8];
  #pragma unroll
  for (int ft = 0; ft < 8; ++ft) acc2[ft] = (f32x4){0.f,0.f,0.f,0.f};
  #pragma unroll
  for (int ks = 0; ks < 4; ++ks){
    #pragma unroll
    for (int ft = 0; ft < 8; ++ft){
      short8 B = *(const short8*)(mb + (size_t)(((ks*8 + ft)*64 + lane)*16));
      acc2[ft] = __builtin_amdgcn_mfma_f32_16x16x32_bf16(Aq[ks], B, acc2[ft], 0, 0, 0);
    }
  }
  float sc = 0.f;
  #pragma unroll
  for (int ft = 0; ft < 8; ++ft){
    #pragma unroll
    for (int r = 0; r < 4; ++r){
      int a = hi*4 + r;
      if (hi < 2 && a < NAq)
        sc += acc2[ft][r] * b2f(*(const unsigned short*)(accB + a*272 + ft*32 + lo*2));
    }
  }
  #pragma unroll
  for (int m = 1; m < 64; m <<= 1) sc += __shfl_xor(sc, m);
  return sc;
}

// ---------------- kernel 2: register-direct A-frags, 1 atom/wave ---------------
__global__ __launch_bounds__(256, 4) void k_main(
    const float* __restrict__ gs, const float* __restrict__ gp,
    const float* __restrict__ gd, const int* __restrict__ nbr,
    char* __restrict__ ws, float* __restrict__ out)
{
  __shared__ alignas(16) char sm[4*8192];
  const int tid = threadIdx.x, lane = tid & 63;
  const int wid = __builtin_amdgcn_readfirstlane(tid >> 6);
  const int lo = lane & 15, hi = lane >> 4;
  const bool valid = lo < NJ;
  const int jc = valid ? lo : NJ-1;
  char* fA   = sm + wid*8192;        // 12 rows * 264 B
  char* fB   = fA + 3264;
  char* accB = fA + 6528;            // 5 rows * 272 B bf16
  const char* gfrag = ws + GFRAG_OFF;
  const char* mfrag = ws + MFRAG_OFF;
  const unsigned short* feaS = (const unsigned short*)(ws + FEA_OFF);
  const unsigned short* feaP = feaS + FEA_ELEMS;
  const unsigned short* feaD = feaS + 2*FEA_ELEMS;
  const float* cfea = (const float*)(ws + CFEA_OFF);

  int rowoff[4];
  #pragma unroll
  for (int r = 0; r < 4; ++r){
    int j = hi*4 + r; if (j > NJ-1) j = NJ-1;
    rowoff[r] = j*264;
  }

  const int atom = (int)blockIdx.x*4 + wid;

  // neighbor indices (lanes 0..11)
  int nb = 0;
  if (lane < NJ) nb = nbr[(size_t)atom*NJ + lane];

  // ---- issue raw g loads (A-fragment-shaped: 8 consecutive k per lane) ----
  const float* gsp = gs + (size_t)atom*384  + (jc*32 + hi*8);
  const float* gpp = gp + (size_t)atom*1152 + (jc*96 + hi*24);
  const float* gdp = gd + (size_t)atom*1920 + (jc*160 + hi*40);

  float sr[8];
  #pragma unroll
  for (int q = 0; q < 2; ++q){
    f32x4 v = *(const f32x4*)(gsp + q*4);
    #pragma unroll
    for (int c = 0; c < 4; ++c) sr[q*4+c] = v[c];
  }
  float pr[24];
  #pragma unroll
  for (int q = 0; q < 6; ++q){
    f32x4 v = *(const f32x4*)(gpp + q*4);
    #pragma unroll
    for (int c = 0; c < 4; ++c) pr[q*4+c] = v[c];
  }

  // stage neighbor fea rows (s -> fA, p -> fB)
  stage_fea(fA, feaS, nb, lane);
  stage_fea(fB, feaP, nb, lane);

  // build s/p fragments
  short8 AfS = frag4(pack_bf2(sr[0],sr[1]), pack_bf2(sr[2],sr[3]),
                     pack_bf2(sr[4],sr[5]), pack_bf2(sr[6],sr[7]), valid);
  short8 AfP[3];
  #pragma unroll
  for (int a = 0; a < 3; ++a)
    AfP[a] = frag4(pack_bf2(pr[0+a], pr[3+a]),  pack_bf2(pr[6+a],  pr[9+a]),
                   pack_bf2(pr[12+a],pr[15+a]), pack_bf2(pr[18+a], pr[21+a]), valid);

  // issue d raw loads (latency hidden under G0)
  float dr[40];
  #pragma unroll
  for (int q = 0; q < 10; ++q){
    f32x4 v = *(const f32x4*)(gdp + q*4);
    #pragma unroll
    for (int c = 0; c < 4; ++c) dr[q*4+c] = v[c];
  }

  lds_fence();   // fA, fB staged

  // ---- G0 (s channel): weighted j-sum -> outv0/outv1 ----
  float outv0 = 0.f, outv1 = 0.f;
  {
    const f32x4 z4 = {0.f,0.f,0.f,0.f};
    short8 Bg[8];
    #pragma unroll
    for (int ft = 0; ft < 8; ++ft)
      Bg[ft] = *(const short8*)(gfrag + (size_t)((ft*64 + lane)*16));
    #pragma unroll
    for (int ft = 0; ft < 8; ++ft){
      int fo = (ft*16 + lo)*2;
      float w0 = b2f(*(const unsigned short*)(fA + rowoff[0] + fo));
      float w1 = b2f(*(const unsigned short*)(fA + rowoff[1] + fo));
      float w2 = b2f(*(const unsigned short*)(fA + rowoff[2] + fo));
      float w3 = b2f(*(const unsigned short*)(fA + rowoff[3] + fo));
      f32x4 c = __builtin_amdgcn_mfma_f32_16x16x32_bf16(AfS, Bg[ft], z4, 0, 0, 0);
      float p = c[0]*w0 + c[1]*w1 + c[2]*w2 + c[3]*w3;
      p += __shfl_xor(p, 16);
      p += __shfl_xor(p, 32);
      if (ft == hi)     outv0 += p;
      if (ft == hi + 4) outv1 += p;
    }
  }
  __builtin_amdgcn_sched_barrier(0);
  // restage fA with d-channel rows (after G0's reads; DS in-order per wave)
  stage_fea(fA, feaD, nb, lane);

  // build d fragments
  short8 AfD[5];
  #pragma unroll
  for (int a = 0; a < 5; ++a)
    AfD[a] = frag4(pack_bf2(dr[0+a], dr[5+a]),  pack_bf2(dr[10+a], dr[15+a]),
                   pack_bf2(dr[20+a], dr[25+a]), pack_bf2(dr[30+a], dr[35+a]), valid);

  // ---- G1 (p channel) -> accB rows 0-2 ----
  jsum_acc<3>(AfP, gfrag + 8192, fB, rowoff, accB, lane);
  lds_fence();   // accB + fA(d) visible
  float qp = quad_head<3>(mfrag, accB, lane, lo, hi);
  __builtin_amdgcn_sched_barrier(0);
  // ---- G2 (d channel) -> accB rows 0-4 (after qp's reads; in-order DS) ----
  jsum_acc<5>(AfD, gfrag + 16384, fA, rowoff, accB, lane);
  lds_fence();
  float qd = quad_head<5>(mfrag + 32768, accB, lane, lo, hi);

  size_t ob = (size_t)atom*FDIM;
  float add = qp + qd;
  out[ob + lane]      = cfea[ob + lane]      + outv0 + add;
  out[ob + 64 + lane] = cfea[ob + 64 + lane] + outv1 + add;
}

// ---------------- launch -------------------------------------------------------
extern "C" void kernel_launch(void* const* d_in, const int* in_sizes, int n_in,
                              void* d_out, int out_size, void* d_ws, size_t ws_size,
                              hipStream_t stream)
{
  const float* atom_fea = (const float*)d_in[0];
  const int*   nbr      = (const int*)d_in[1];
  const float* gs = (const float*)d_in[2];
  const float* gp = (const float*)d_in[3];
  const float* gd = (const float*)d_in[4];
  const float* Gs = (const float*)d_in[5];
  const float* Gp = (const float*)d_in[6];
  const float* Gd = (const float*)d_in[7];
  const float* P1 = (const float*)d_in[8];
  const float* P2 = (const float*)d_in[9];
  const float* D1 = (const float*)d_in[10];
  const float* D2 = (const float*)d_in[11];

  Ptr8 w8;
  w8.p[0] = (const float*)d_in[12];  // c_wr
  w8.p[1] = (const float*)d_in[14];  // c_w1
  w8.p[2] = (const float*)d_in[16];  // s_wr
  w8.p[3] = (const float*)d_in[18];  // s_w1
  w8.p[4] = (const float*)d_in[20];  // p_wr
  w8.p[5] = (const float*)d_in[22];  // p_w1
  w8.p[6] = (const float*)d_in[24];  // d_wr
  w8.p[7] = (const float*)d_in[26];  // d_w1
  Ptr3 g3; g3.p[0] = Gs; g3.p[1] = Gp; g3.p[2] = Gd;
  Bias bs;
  bs.br[0] = (const float*)d_in[13]; bs.b1[0] = (const float*)d_in[15];
  bs.br[1] = (const float*)d_in[17]; bs.b1[1] = (const float*)d_in[19];
  bs.br[2] = (const float*)d_in[21]; bs.b1[2] = (const float*)d_in[23];
  bs.br[3] = (const float*)d_in[25]; bs.b1[3] = (const float*)d_in[27];

  char* ws = (char*)d_ws;
  float* out = (float*)d_out;

  k_prep  <<<27, 256, 0, stream>>>(P1, P2, D1, D2, w8, g3, ws);
  k_resmlp<<<(N_ATOMS + 63)/64, 256, 0, stream>>>(atom_fea, ws, bs);
  k_main  <<<N_ATOMS/4, 256, 0, stream>>>(gs, gp, gd, nbr, ws, out);
}